// Round 2
// baseline (186.183 us; speedup 1.0000x reference)
//
#include <hip/hip_runtime.h>

#define N_ITER 100

typedef float f32x4 __attribute__((ext_vector_type(4)));
typedef unsigned u32x4 __attribute__((ext_vector_type(4)));

// RNE-pack two f32 into a dword of two bf16 (proven R7-R16: absmax 3.9e-3).
__device__ __forceinline__ unsigned bf16pack(float a, float b) {
  unsigned ua = __float_as_uint(a), ub = __float_as_uint(b);
  ua = (ua + 0x7FFFu + ((ua >> 16) & 1u)) >> 16;
  ub = (ub + 0x7FFFu + ((ub >> 16) & 1u)) >> 16;
  return ua | (ub << 16);
}
__device__ __forceinline__ float bflo(unsigned u) { return __uint_as_float(u << 16); }
__device__ __forceinline__ float bfhi(unsigned u) { return __uint_as_float(u & 0xFFFF0000u); }

// Force a value's virtual register into AGPR class AT DEFINITION (proven R13).
__device__ __forceinline__ void pin_agpr(u32x4& x) {
  asm("" : "=a"(x) : "0"(x));
}

// MFMA: A in AGPR (pinned frags), B in VGPR (ds_read), acc in VGPR.
// R17 hazard audit still holds: interior MFMAs read only B (waitcnt-
// protected ds_read results), A (AGPR, pinned far away) and acc (MFMA->MFMA
// same-pipe chain, HW-interlocked). One s_nop 2 at phase start as insurance;
// 24-cyc data-tied exit fence before any VALU reads MFMA destinations.
__device__ __forceinline__ void mfma_first_nop(f32x4& acc, const u32x4& a, const u32x4& b) {
  asm("s_nop 2\n\tv_mfma_f32_16x16x32_bf16 %0, %1, %2, 0"
      : "=&v"(acc) : "a"(a), "v"(b));
}
__device__ __forceinline__ void mfma_first(f32x4& acc, const u32x4& a, const u32x4& b) {
  asm("v_mfma_f32_16x16x32_bf16 %0, %1, %2, 0"
      : "=&v"(acc) : "a"(a), "v"(b));
}
__device__ __forceinline__ void mfma_aa(f32x4& acc, const u32x4& a, const u32x4& b) {
  asm("v_mfma_f32_16x16x32_bf16 %0, %1, %2, %0"
      : "+v"(acc) : "a"(a), "v"(b));
}
// Data-tied 24-cyc fence on all 8 accumulators before VALU touches them.
__device__ __forceinline__ void mfma_fence8(f32x4& a0, f32x4& a1, f32x4& a2, f32x4& a3,
                                            f32x4& a4, f32x4& a5, f32x4& a6, f32x4& a7) {
  asm volatile("s_nop 7\n\ts_nop 7\n\ts_nop 7"
               : "+v"(a0), "+v"(a1), "+v"(a2), "+v"(a3),
                 "+v"(a4), "+v"(a5), "+v"(a6), "+v"(a7));
}

// 8 waves (512 threads) per matrix, wave w owns rows/cols [32w,32w+32)
// (R13 structure, proven 123 us). R18 lesson (4-wave A/B): phase time is a
// serial LATENCY chain, not LDS/issue throughput. This version cuts the
// dependent-MFMA chain depth 8 -> 2: per slab, 4 parallel accumulators over
// K-chunk pairs {u, u+4}, tree-added after the fence. All 16 chains are
// interleaved so each chain link has ~8 intervening MFMAs (dep latency
// hidden); MFMA region becomes issue-limited. Tail spread over lanes m<2
// (slab s=m): 4 rcps each instead of 8 serial on m==0.
// Layouts (m89-verified): A elem j <-> A[m=lane&15][k=8q+j]; D reg r <-> row
// 4q+r, col=lane&15 (row-sum result broadcast over all 16 n-cols).
__global__ __launch_bounds__(512)
__attribute__((amdgpu_waves_per_eu(2, 2)))
void sinkhorn_mfma8d2(const float* __restrict__ alpha, float* __restrict__ out) {
  __shared__ alignas(16) unsigned short Cb16[256];
  __shared__ alignas(16) unsigned short Rb16[256];
  __shared__ alignas(16) float Cb32[256];
  __shared__ alignas(16) float Rb32[256];

  const int tid  = threadIdx.x;
  const int lane = tid & 63;
  const int w    = tid >> 6;   // wave 0..7
  const int m    = lane & 15;
  const int q    = lane >> 4;

  const size_t mbase = (size_t)blockIdx.x * (256 * 256);
  const float* A = alpha + mbase;
  float*       O = out + mbase;

  // arow[s][c] elem j <-> V0[32w+16s+m][32c+8q+j]
  // acol[s][c] elem j <-> V0[32c+8q+j][32w+16s+m]
  u32x4 arow[2][8];
  u32x4 acol[2][8];

#pragma unroll
  for (int s = 0; s < 2; ++s) {
    const float* rowp = A + (size_t)(32 * w + 16 * s + m) * 256 + 8 * q;
#pragma unroll
    for (int c = 0; c < 8; ++c) {
      float4 x0 = *(const float4*)(rowp + 32 * c);
      float4 x1 = *(const float4*)(rowp + 32 * c + 4);
      arow[s][c] = (u32x4){bf16pack(__expf(x0.x * 10.0f), __expf(x0.y * 10.0f)),
                           bf16pack(__expf(x0.z * 10.0f), __expf(x0.w * 10.0f)),
                           bf16pack(__expf(x1.x * 10.0f), __expf(x1.y * 10.0f)),
                           bf16pack(__expf(x1.z * 10.0f), __expf(x1.w * 10.0f))};
    }
    const float* colp = A + (size_t)(8 * q) * 256 + 32 * w + 16 * s + m;
#pragma unroll
    for (int c = 0; c < 8; ++c) {
      const float* p = colp + (size_t)(32 * c) * 256;
      acol[s][c] =
          (u32x4){bf16pack(__expf(p[0] * 10.0f), __expf(p[256] * 10.0f)),
                  bf16pack(__expf(p[512] * 10.0f), __expf(p[768] * 10.0f)),
                  bf16pack(__expf(p[1024] * 10.0f), __expf(p[1280] * 10.0f)),
                  bf16pack(__expf(p[1536] * 10.0f), __expf(p[1792] * 10.0f))};
    }
  }
  // Pin all persistent fragments into AGPRs (one-time, far from MFMAs).
#pragma unroll
  for (int s = 0; s < 2; ++s)
#pragma unroll
    for (int c = 0; c < 8; ++c) {
      pin_agpr(arow[s][c]);
      pin_agpr(acol[s][c]);
    }

  if (tid < 256) Cb16[tid] = 0x3F80;  // C = 1
  __syncthreads();

  for (int it = 0; it < N_ITER; ++it) {
    const bool last = (it == N_ITER - 1);

    // ---------- phase 1: s = V0_rowslabs · C ; R = 1/s ----------
    {
      u32x4 B[8];
#pragma unroll
      for (int c = 0; c < 8; ++c) B[c] = *(const u32x4*)&Cb16[32 * c + 8 * q];
      // 16 chains of depth 2: acc[s][u] accumulates chunks {u, u+4}.
      f32x4 a00, a01, a02, a03, a10, a11, a12, a13;
      mfma_first_nop(a00, arow[0][0], B[0]);
      mfma_first(a10, arow[1][0], B[0]);
      mfma_first(a01, arow[0][1], B[1]);
      mfma_first(a11, arow[1][1], B[1]);
      mfma_first(a02, arow[0][2], B[2]);
      mfma_first(a12, arow[1][2], B[2]);
      mfma_first(a03, arow[0][3], B[3]);
      mfma_first(a13, arow[1][3], B[3]);
      mfma_aa(a00, arow[0][4], B[4]);
      mfma_aa(a10, arow[1][4], B[4]);
      mfma_aa(a01, arow[0][5], B[5]);
      mfma_aa(a11, arow[1][5], B[5]);
      mfma_aa(a02, arow[0][6], B[6]);
      mfma_aa(a12, arow[1][6], B[6]);
      mfma_aa(a03, arow[0][7], B[7]);
      mfma_aa(a13, arow[1][7], B[7]);
      mfma_fence8(a00, a01, a02, a03, a10, a11, a12, a13);
      f32x4 s0 = (a00 + a01) + (a02 + a03);
      f32x4 s1 = (a10 + a11) + (a12 + a13);
      if (m < 2) {  // lane (m,q) handles slab s=m: rows 32w+16m+4q..+3
        f32x4 sv = m ? s1 : s0;
        float r0 = __builtin_amdgcn_rcpf(sv[0]);
        float r1 = __builtin_amdgcn_rcpf(sv[1]);
        float r2 = __builtin_amdgcn_rcpf(sv[2]);
        float r3 = __builtin_amdgcn_rcpf(sv[3]);
        *(uint2*)&Rb16[32 * w + 16 * m + 4 * q] =
            make_uint2(bf16pack(r0, r1), bf16pack(r2, r3));
        if (last)
          *(float4*)&Rb32[32 * w + 16 * m + 4 * q] = make_float4(r0, r1, r2, r3);
      }
    }
    __syncthreads();

    // ---------- phase 2: t = V0^T_colslabs · R ; C = 1/t ----------
    {
      u32x4 B[8];
#pragma unroll
      for (int c = 0; c < 8; ++c) B[c] = *(const u32x4*)&Rb16[32 * c + 8 * q];
      f32x4 a00, a01, a02, a03, a10, a11, a12, a13;
      mfma_first_nop(a00, acol[0][0], B[0]);
      mfma_first(a10, acol[1][0], B[0]);
      mfma_first(a01, acol[0][1], B[1]);
      mfma_first(a11, acol[1][1], B[1]);
      mfma_first(a02, acol[0][2], B[2]);
      mfma_first(a12, acol[1][2], B[2]);
      mfma_first(a03, acol[0][3], B[3]);
      mfma_first(a13, acol[1][3], B[3]);
      mfma_aa(a00, acol[0][4], B[4]);
      mfma_aa(a10, acol[1][4], B[4]);
      mfma_aa(a01, acol[0][5], B[5]);
      mfma_aa(a11, acol[1][5], B[5]);
      mfma_aa(a02, acol[0][6], B[6]);
      mfma_aa(a12, acol[1][6], B[6]);
      mfma_aa(a03, acol[0][7], B[7]);
      mfma_aa(a13, acol[1][7], B[7]);
      mfma_fence8(a00, a01, a02, a03, a10, a11, a12, a13);
      f32x4 s0 = (a00 + a01) + (a02 + a03);
      f32x4 s1 = (a10 + a11) + (a12 + a13);
      if (m < 2) {  // lane (m,q) handles slab s=m: cols 32w+16m+4q..+3
        f32x4 sv = m ? s1 : s0;
        float c0 = __builtin_amdgcn_rcpf(sv[0]);
        float c1 = __builtin_amdgcn_rcpf(sv[1]);
        float c2 = __builtin_amdgcn_rcpf(sv[2]);
        float c3 = __builtin_amdgcn_rcpf(sv[3]);
        *(uint2*)&Cb16[32 * w + 16 * m + 4 * q] =
            make_uint2(bf16pack(c0, c1), bf16pack(c2, c3));
        if (last)
          *(float4*)&Cb32[32 * w + 16 * m + 4 * q] = make_float4(c0, c1, c2, c3);
      }
    }
    __syncthreads();
  }

  // ---------- epilogue: out = diag(R32) · V0_bf16 · diag(C32) ----------
#pragma unroll
  for (int s = 0; s < 2; ++s) {
    const float Rm = Rb32[32 * w + 16 * s + m];
    float* dst = O + (size_t)(32 * w + 16 * s + m) * 256 + 8 * q;
#pragma unroll
    for (int c = 0; c < 8; ++c) {
      float4 c0 = *(const float4*)&Cb32[32 * c + 8 * q];
      float4 c1 = *(const float4*)&Cb32[32 * c + 8 * q + 4];
      u32x4 pk = arow[s][c];
      float4 o0, o1;
      o0.x = bflo(pk.x) * Rm * c0.x;
      o0.y = bfhi(pk.x) * Rm * c0.y;
      o0.z = bflo(pk.y) * Rm * c0.z;
      o0.w = bfhi(pk.y) * Rm * c0.w;
      o1.x = bflo(pk.z) * Rm * c1.x;
      o1.y = bfhi(pk.z) * Rm * c1.y;
      o1.z = bflo(pk.w) * Rm * c1.z;
      o1.w = bfhi(pk.w) * Rm * c1.w;
      *(float4*)(dst + 32 * c) = o0;
      *(float4*)(dst + 32 * c + 4) = o1;
    }
  }
}

extern "C" void kernel_launch(void* const* d_in, const int* in_sizes, int n_in,
                              void* d_out, int out_size, void* d_ws, size_t ws_size,
                              hipStream_t stream) {
  const float* alpha = (const float*)d_in[0];
  float* out = (float*)d_out;
  sinkhorn_mfma8d2<<<dim3(16), dim3(512), 0, stream>>>(alpha, out);
}

// Round 3
// 175.893 us; speedup vs baseline: 1.0585x; 1.0585x over previous
//
#include <hip/hip_runtime.h>

#define N_ITER 100

typedef float f32x4 __attribute__((ext_vector_type(4)));
typedef unsigned u32x4 __attribute__((ext_vector_type(4)));

// RNE-pack two f32 into a dword of two bf16 (proven R7-R16: absmax 3.9e-3).
__device__ __forceinline__ unsigned bf16pack(float a, float b) {
  unsigned ua = __float_as_uint(a), ub = __float_as_uint(b);
  ua = (ua + 0x7FFFu + ((ua >> 16) & 1u)) >> 16;
  ub = (ub + 0x7FFFu + ((ub >> 16) & 1u)) >> 16;
  return ua | (ub << 16);
}
__device__ __forceinline__ float bflo(unsigned u) { return __uint_as_float(u << 16); }
__device__ __forceinline__ float bfhi(unsigned u) { return __uint_as_float(u & 0xFFFF0000u); }

// Force a value's virtual register into AGPR class AT DEFINITION (proven R13).
__device__ __forceinline__ void pin_agpr(u32x4& x) {
  asm("" : "=a"(x) : "0"(x));
}

// MFMA with A + accumulator handling per proven R13/R17 structure.
__device__ __forceinline__ void mfma_first_nop(f32x4& acc, const u32x4& a, const u32x4& b) {
  asm("s_nop 2\n\tv_mfma_f32_16x16x32_bf16 %0, %1, %2, 0"
      : "=&a"(acc) : "a"(a), "v"(b));
}
__device__ __forceinline__ void mfma_first(f32x4& acc, const u32x4& a, const u32x4& b) {
  asm("v_mfma_f32_16x16x32_bf16 %0, %1, %2, 0"
      : "=&a"(acc) : "a"(a), "v"(b));
}
__device__ __forceinline__ void mfma_aa(f32x4& acc, const u32x4& a, const u32x4& b) {
  asm("v_mfma_f32_16x16x32_bf16 %0, %1, %2, %0"
      : "+a"(acc) : "a"(a), "v"(b));
}
__device__ __forceinline__ void mfma_fence(f32x4& acc0, f32x4& acc1) {
  asm volatile("s_nop 7\n\ts_nop 7\n\ts_nop 7" : "+a"(acc0), "+a"(acc1));
}

// 8 waves (512 threads) per matrix; wave w owns rows/cols [32w,32w+32).
// EXACT R13/R0 123us structure (depth-8 chains, 2 accs -- R1/R2 A/Bs proved
// LDS throughput and MFMA-chain latency are NOT the bottleneck; both
// restructures regressed). R3 changes ONLY the serial tail:
//  (a) rcp/pack/write spread over lanes m<2 (4 rcps + 1 b64 write each)
//      instead of 8 serial rcps + 2 writes in lane m==0;
//  (b) last iteration peeled: no `last` branch / f32-store path in the 199
//      hot phases; final phase 2 skips the dead Cb16 write.
// Layouts (m89-verified): A elem j <-> A[m=lane&15][k=8q+j]; D reg r <-> row
// 4q+r, col=lane&15.
__global__ __launch_bounds__(512)
__attribute__((amdgpu_waves_per_eu(2, 2)))
void sinkhorn_mfma8t(const float* __restrict__ alpha, float* __restrict__ out) {
  __shared__ alignas(16) unsigned short Cb16[256];
  __shared__ alignas(16) unsigned short Rb16[256];
  __shared__ alignas(16) float Cb32[256];
  __shared__ alignas(16) float Rb32[256];

  const int tid  = threadIdx.x;
  const int lane = tid & 63;
  const int w    = tid >> 6;   // wave 0..7
  const int m    = lane & 15;
  const int q    = lane >> 4;

  const size_t mbase = (size_t)blockIdx.x * (256 * 256);
  const float* A = alpha + mbase;
  float*       O = out + mbase;

  // arow[s][c] elem j <-> V0[32w+16s+m][32c+8q+j]
  // acol[s][c] elem j <-> V0[32c+8q+j][32w+16s+m]
  u32x4 arow[2][8];
  u32x4 acol[2][8];

#pragma unroll
  for (int s = 0; s < 2; ++s) {
    const float* rowp = A + (size_t)(32 * w + 16 * s + m) * 256 + 8 * q;
#pragma unroll
    for (int c = 0; c < 8; ++c) {
      float4 x0 = *(const float4*)(rowp + 32 * c);
      float4 x1 = *(const float4*)(rowp + 32 * c + 4);
      arow[s][c] = (u32x4){bf16pack(__expf(x0.x * 10.0f), __expf(x0.y * 10.0f)),
                           bf16pack(__expf(x0.z * 10.0f), __expf(x0.w * 10.0f)),
                           bf16pack(__expf(x1.x * 10.0f), __expf(x1.y * 10.0f)),
                           bf16pack(__expf(x1.z * 10.0f), __expf(x1.w * 10.0f))};
    }
    const float* colp = A + (size_t)(8 * q) * 256 + 32 * w + 16 * s + m;
#pragma unroll
    for (int c = 0; c < 8; ++c) {
      const float* p = colp + (size_t)(32 * c) * 256;
      acol[s][c] =
          (u32x4){bf16pack(__expf(p[0] * 10.0f), __expf(p[256] * 10.0f)),
                  bf16pack(__expf(p[512] * 10.0f), __expf(p[768] * 10.0f)),
                  bf16pack(__expf(p[1024] * 10.0f), __expf(p[1280] * 10.0f)),
                  bf16pack(__expf(p[1536] * 10.0f), __expf(p[1792] * 10.0f))};
    }
  }
  // Pin all persistent fragments into AGPRs (one-time, far from MFMAs).
#pragma unroll
  for (int s = 0; s < 2; ++s)
#pragma unroll
    for (int c = 0; c < 8; ++c) {
      pin_agpr(arow[s][c]);
      pin_agpr(acol[s][c]);
    }

  if (tid < 256) Cb16[tid] = 0x3F80;  // C = 1
  __syncthreads();

  // One normalization phase: sums = FRAG . SRC16 ; DST = 1/sums.
  // W16: write bf16 scales (needed by the next phase); W32: write f32 scales
  // (needed only by the epilogue). Literal flags fold at compile time.
#define PHASE(FRAG, SRC16, DST16, DST32, W16, W32)                         \
  {                                                                        \
    u32x4 Bv[8];                                                           \
    _Pragma("unroll")                                                      \
    for (int c = 0; c < 8; ++c) Bv[c] = *(const u32x4*)&SRC16[32 * c + 8 * q]; \
    f32x4 acc0, acc1;                                                      \
    mfma_first_nop(acc0, FRAG[0][0], Bv[0]);                               \
    mfma_first(acc1, FRAG[1][0], Bv[0]);                                   \
    _Pragma("unroll")                                                      \
    for (int c = 1; c < 8; ++c) {                                          \
      mfma_aa(acc0, FRAG[0][c], Bv[c]);                                    \
      mfma_aa(acc1, FRAG[1][c], Bv[c]);                                    \
    }                                                                      \
    mfma_fence(acc0, acc1);                                                \
    if (m < 2) { /* lane (m,q) owns slab s=m: rows/cols 32w+16m+4q..+3 */  \
      f32x4 sv = m ? acc1 : acc0;                                          \
      float r0 = __builtin_amdgcn_rcpf(sv[0]);                             \
      float r1 = __builtin_amdgcn_rcpf(sv[1]);                             \
      float r2 = __builtin_amdgcn_rcpf(sv[2]);                             \
      float r3 = __builtin_amdgcn_rcpf(sv[3]);                             \
      if (W16)                                                             \
        *(uint2*)&DST16[32 * w + 16 * m + 4 * q] =                         \
            make_uint2(bf16pack(r0, r1), bf16pack(r2, r3));                \
      if (W32)                                                             \
        *(float4*)&DST32[32 * w + 16 * m + 4 * q] =                        \
            make_float4(r0, r1, r2, r3);                                   \
    }                                                                      \
  }                                                                        \
  __syncthreads();

  for (int it = 0; it < N_ITER - 1; ++it) {
    PHASE(arow, Cb16, Rb16, Rb32, 1, 0)   // R = 1/(V0_rows . C)
    PHASE(acol, Rb16, Cb16, Cb32, 1, 0)   // C = 1/(V0^T_cols . R)
  }
  // Peeled final iteration: also produce f32 scales for the epilogue.
  PHASE(arow, Cb16, Rb16, Rb32, 1, 1)
  PHASE(acol, Rb16, Cb16, Cb32, 0, 1)     // Cb16 dead after this -> skip
#undef PHASE

  // ---------- epilogue: out = diag(R32) · V0_bf16 · diag(C32) ----------
#pragma unroll
  for (int s = 0; s < 2; ++s) {
    const float Rm = Rb32[32 * w + 16 * s + m];
    float* dst = O + (size_t)(32 * w + 16 * s + m) * 256 + 8 * q;
#pragma unroll
    for (int c = 0; c < 8; ++c) {
      float4 c0 = *(const float4*)&Cb32[32 * c + 8 * q];
      float4 c1 = *(const float4*)&Cb32[32 * c + 8 * q + 4];
      u32x4 pk = arow[s][c];
      float4 o0, o1;
      o0.x = bflo(pk.x) * Rm * c0.x;
      o0.y = bfhi(pk.x) * Rm * c0.y;
      o0.z = bflo(pk.y) * Rm * c0.z;
      o0.w = bfhi(pk.y) * Rm * c0.w;
      o1.x = bflo(pk.z) * Rm * c1.x;
      o1.y = bfhi(pk.z) * Rm * c1.y;
      o1.z = bflo(pk.w) * Rm * c1.z;
      o1.w = bfhi(pk.w) * Rm * c1.w;
      *(float4*)(dst + 32 * c) = o0;
      *(float4*)(dst + 32 * c + 4) = o1;
    }
  }
}

extern "C" void kernel_launch(void* const* d_in, const int* in_sizes, int n_in,
                              void* d_out, int out_size, void* d_ws, size_t ws_size,
                              hipStream_t stream) {
  const float* alpha = (const float*)d_in[0];
  float* out = (float*)d_out;
  sinkhorn_mfma8t<<<dim3(16), dim3(512), 0, stream>>>(alpha, out);
}